// Round 3
// baseline (134.460 us; speedup 1.0000x reference)
//
#include <hip/hip_runtime.h>
#include <math.h>

// ONE RAY PER THREAD (R10). History: R7's tpr=2/ILP-2 choice was made on the
// fat sigmoid-heavy kernel (issue-bound, busy~96k cy/wave). R9's recurrence
// diet made the kernel latency-bound: 190k cy/wave = 85k VALU-issue + 105k
// dependency bubbles (~4.5 cy/instr), invariant across R0-R2. Bubbles need
// PARALLELISM, not fewer instructions. tpr=1 doubles waves: 2048 waves =
// 2 waves/SIMD -- hardware round-robin fills each wave's dep bubbles with the
// other wave's ready instructions (no VGPR cost, no scheduler luck, hides
// trans + ds_read latency). fd LDS halves to 16.6KB/block -> 8 blocks/CU ✓.
// R9 numerics kept exactly: exp2 geometric recurrence on the uniform coarse
// grid (phases 1+2 have ZERO exp2 in their loops); phase 3 depths are
// data-dependent -> full sigmoids there.
// Phase 2/3 fully branchless: conditional LDS store -> unconditional store to
// pad row; window refill -> unconditional ds_read. fd columns are per-thread
// only -> zero barriers.

#define NT 64
#define PTS 64
#define NRAYS (2*256*256)
#define NEARV 0.1f
#define STEPV (1.9f/63.0f)
#define FAR63 (0.1f + 63.0f*(1.9f/63.0f))
#define NL2E (-1.4426950408889634f)

__device__ __forceinline__ float sig_pm(float arg) {   // arg is already -x*log2e
    return __builtin_amdgcn_rcpf(1.0f + __builtin_amdgcn_exp2f(arg));
}
__device__ __forceinline__ float sig_e(float e) {      // e = exp2(-x*log2e)
    return __builtin_amdgcn_rcpf(1.0f + e);
}

__global__ __launch_bounds__(NT, 2) void nerf_main(
    const float* __restrict__ tm, const float* __restrict__ wq,
    float* __restrict__ out, unsigned int* __restrict__ mmx)
{
    __shared__ float fd[PTS + 1][NT];      // per-ray fine depths + junk pad row
    const int tid = threadIdx.x;
    const int r = blockIdx.x * NT + tid;
    const int b = r >> 16, n = r & 65535;
    const int i = n >> 8, j = n & 255;

    float bA[4], sA[4];                    // feat[c]*(-log2e) = bA + d*sA
    {
        float cx = (1.0f + (float)j * (-2.0f/255.0f)) * (1.0f/4.2f);
        float cy = (1.0f + (float)i * (-2.0f/255.0f)) * (1.0f/4.2f);
        const float* tmb = tm + b*12;
        float dx = tmb[0]*cx + tmb[1]*cy + tmb[2];
        float dy = tmb[4]*cx + tmb[5]*cy + tmb[6];
        float dz = tmb[8]*cx + tmb[9]*cy + tmb[10];
        float ox = tmb[3], oy = tmb[7], oz = tmb[11];
        #pragma unroll
        for (int c = 0; c < 4; c++) {
            float s  = dx*wq[0*4+c] + dy*wq[1*4+c] + dz*wq[2*4+c];
            float bv = ox*wq[0*4+c] + oy*wq[1*4+c] + oz*wq[2*4+c]
                     + dx*wq[3*4+c] + dy*wq[4*4+c] + dz*wq[5*4+c];
            sA[c] = s * NL2E;
            bA[c] = bv * NL2E;
        }
    }

    // recurrence state: eV[c] = exp2(bA + d*sA) at the current coarse point,
    // kV[c] = per-step ratio exp2(sA*STEP). e00 = eV[0] at d = NEAR.
    float eV[4], kV[4], e00;
    #pragma unroll
    for (int c = 0; c < 4; c++) {
        eV[c] = __builtin_amdgcn_exp2f(bA[c] + NEARV*sA[c]);
        kV[c] = __builtin_amdgcn_exp2f(sA[c]*STEPV);
    }
    e00 = eV[0];

    // ---- phase 1: coarse march, zero exp2 ----
    float T = 1.0f, S = 0.0f;
    float a0 = 0.0f, a1 = 0.0f, a2 = 0.0f;
    #pragma unroll 4
    for (int p = 0; p < PTS; p++) {
        float op = sig_e(eV[0]);
        float v0 = sig_e(eV[1]);
        float v1 = sig_e(eV[2]);
        float v2 = sig_e(eV[3]);
        eV[0] *= kV[0];
        eV[1] *= kV[1];
        eV[2] *= kV[2];
        eV[3] *= kV[3];
        float w  = op * T;
        a0 = fmaf(w, v0, a0);
        a1 = fmaf(w, v1, a1);
        a2 = fmaf(w, v2, a2);
        S += w + 1e-5f;
        T *= (1.0f - op);
    }
    out[(b*3+0)*65536 + n] = a0;
    out[(b*3+1)*65536 + n] = a1;
    out[(b*3+2)*65536 + n] = a2;

    // ---- phase 2: branchless sampling machine, zero exp2 ----
    // eP tracks exp2-value at coarse index m = min(ind+1, 63); advance is one
    // conditional multiply by kV[0].
    float Sinv = __builtin_amdgcn_rcpf(S);
    float op0  = sig_e(e00);                 // sigmoid at d = NEAR (index 0)
    float T2   = 1.0f - op0;
    float c_lo = 0.0f;
    float c_hi = (op0 + 1e-5f) * Sinv;       // cdf[0]
    int ind = 0, kk = 1;
    float bin_prev = NEARV;                  // bin_0 == NEAR always
    float eP = e00 * kV[0];                  // index m = 1
    #pragma unroll 2
    for (int it = 0; it < 2*PTS; it++) {
        float u = (float)kk * 0.015625f;             // exact k/64
        bool adv = (ind < PTS) && (c_hi <= u);       // searchsorted 'right'
        float opn = sig_e(eP);                       // sigmoid at index m
        float wn  = opn * T2;
        float d0  = fmaf((float)(ind - 1), STEPV, NEARV);
        float den = c_hi - c_lo;
        den = (den < 1e-8f) ? 1.0f : den;            // ref guard
        float t = (u - c_lo) * __builtin_amdgcn_rcpf(den);
        t = fminf(fmaxf(t, 0.0f), 1.0f);
        float bin = fmaf(t, STEPV, d0);
        bin = (ind <= 0)   ? NEARV : bin;
        bin = (ind >= PTS) ? FAR63 : bin;
        float fdep = 0.5f * (bin_prev + bin);
        int widx = adv ? PTS : min(kk - 1, PTS);     // pad row on advance
        fd[widx][tid] = fdep;                        // unconditional ds_write
        float nc_hi = c_hi + (wn + 1e-5f) * Sinv;
        float nT2   = T2 * (1.0f - opn);
        // m = min(ind+1,63) increments iff adv && ind < 62
        float km    = (adv && (ind < 62)) ? kV[0] : 1.0f;
        c_lo     = adv ? c_hi : c_lo;
        c_hi     = adv ? nc_hi : c_hi;
        T2       = adv ? nT2 : T2;
        bin_prev = adv ? bin_prev : bin;
        eP      *= km;
        ind += adv ? 1 : 0;
        kk  += adv ? 0 : 1;
    }

    // ---- phase 3: branchless merge ----
    float T3 = 1.0f, sw = 0.0f;
    float f0 = 0.0f, f1 = 0.0f, f2 = 0.0f;
    float rd = 0.0f;
    int pc = 0, pf = 0;
    float dc = NEARV;
    float cur = fd[0][tid], nxt = fd[1][tid];
    #pragma unroll 2
    for (int it = 0; it < 2*PTS; it++) {
        float dfv = (pf < PTS) ? cur : 3.0e38f;
        bool tc = (pc < PTS) && (dc <= dfv);         // ties -> coarse (stable)
        float d = tc ? dc : dfv;
        pc += tc ? 1 : 0;
        dc = fmaf((float)pc, STEPV, NEARV);
        pf += tc ? 0 : 1;
        cur = tc ? cur : nxt;
        nxt = fd[min(pf + 1, PTS)][tid];             // unconditional ds_read
        float op = sig_pm(bA[0] + d*sA[0]);
        float v0 = sig_pm(bA[1] + d*sA[1]);
        float v1 = sig_pm(bA[2] + d*sA[2]);
        float v2 = sig_pm(bA[3] + d*sA[3]);
        float w  = op * T3;
        f0 = fmaf(w, v0, f0);
        f1 = fmaf(w, v1, f1);
        f2 = fmaf(w, v2, f2);
        sw += w;
        rd = fmaf(w, d, rd);
        T3 *= (1.0f - op);
    }

    out[393216 + (b*3+0)*65536 + n] = f0;
    out[393216 + (b*3+1)*65536 + n] = f1;
    out[393216 + (b*3+2)*65536 + n] = f2;
    float fop  = fminf(fmaxf(sw, 0.0f), 1.0f);
    float rdep = rd + (1.0f - fop) * 2.0f;           // d_all.max() == 2.0 exactly
    out[786432 + r] = rdep;

    unsigned ub  = __float_as_uint(rdep);            // rdep>0: u32 order == float order
    unsigned kmn = ub;
    unsigned kmx = ~ub;
    #pragma unroll
    for (int m = 32; m >= 1; m >>= 1) {
        unsigned omn = (unsigned)__shfl_xor((int)kmn, m, 64);
        unsigned omx = (unsigned)__shfl_xor((int)kmx, m, 64);
        kmn = (omn < kmn) ? omn : kmn;
        kmx = (omx < kmx) ? omx : kmx;
    }
    if (tid == 0) {
        atomicMin(&mmx[0], kmn);
        atomicMin(&mmx[1], kmx);
    }
}

__global__ __launch_bounds__(256) void nerf_norm(float* __restrict__ out,
                                                 const unsigned int* __restrict__ mmx)
{
    int idx = blockIdx.x * 256 + threadIdx.x;
    float mn = __uint_as_float(mmx[0]);
    float mx = __uint_as_float(~mmx[1]);
    float v = out[786432 + idx];
    out[786432 + idx] = (v - mn) * __builtin_amdgcn_rcpf(mx - mn);
}

extern "C" void kernel_launch(void* const* d_in, const int* in_sizes, int n_in,
                              void* d_out, int out_size, void* d_ws, size_t ws_size,
                              hipStream_t stream) {
    (void)in_sizes; (void)n_in; (void)out_size; (void)ws_size;
    const float* tm = (const float*)d_in[0];
    const float* wq = (const float*)d_in[1];
    float* out = (float*)d_out;
    unsigned int* mmx = (unsigned int*)d_ws;
    hipMemsetAsync(d_ws, 0xFF, 8, stream);     // both min-keys -> UINT_MAX
    nerf_main<<<NRAYS/NT, NT, 0, stream>>>(tm, wq, out, mmx);
    nerf_norm<<<NRAYS/256, 256, 0, stream>>>(out, mmx);
}